// Round 4
// baseline (94.961 us; speedup 1.0000x reference)
//
#include <hip/hip_runtime.h>

// LRP m-rule backward through AdaptiveAvgPool2d (56x56 -> 7x7, window 8x8, k=64).
//
// theta = 180deg => COS_T = -1.0 exactly, SIN_T ~ 1.2e-16. The chain collapses:
//   out_i = x_i * r / (Sx + 32*eps),  Sx = window sum (fp64: denominator can
// nearly cancel, min |denom| ~8e-7 over 401K windows). Divide in fp32.
//
// Round-4 layout: one wave = 16 windows, 4-lane team per window.
//   w = lane>>2 (window), t = lane&3 (team lane); lane owns rows {2t, 2t+1}
//   of its 8x8 window = 4 float4 loads (64 B/lane in flight) -> butterfly is
//   only 2 shuffle rounds (xor 1,2), vs 4 rounds / 16 B in round-3. Full
//   unroll of the 4 iterations gives up to 16 independent loads in flight.
// Nontemporal stores keep `out` from evicting `x` in the 256 MiB L3.
//
// Grid: 25088 wave-groups = 6272 waves x 4 iters exact; 1568 blocks x 4 waves.

typedef float f32x4 __attribute__((ext_vector_type(4)));

static constexpr int HW     = 56 * 56;          // 3136
static constexpr int NWIN   = 8192 * 49;        // 401408 windows
static constexpr int NGRP   = NWIN / 16;        // 25088 wave-iterations
static constexpr int BLOCKS = 1568;
static constexpr int WAVES  = BLOCKS * 4;       // 6272
static constexpr int NITER  = NGRP / WAVES;     // 4 (exact)

__global__ __launch_bounds__(256) void lrp_pool_kernel(
    const float* __restrict__ x,
    const float* __restrict__ r,
    float* __restrict__ out)
{
    const int tid  = threadIdx.x;
    const int lane = tid & 63;
    const int w    = lane >> 2;   // window within the wave's group of 16
    const int t    = lane & 3;    // team lane: rows 2t, 2t+1

    const int g0 = blockIdx.x * 4 + (tid >> 6);

    #pragma unroll
    for (int it = 0; it < NITER; ++it) {
        const int g   = g0 + it * WAVES;
        const int wid = g * 16 + w;
        const int bc  = wid / 49;              // magic-mul div
        const int rem = wid - bc * 49;
        const int ohi = rem / 7;
        const int owi = rem - ohi * 7;

        const int base = bc * HW + (ohi * 8 + t * 2) * 56 + owi * 8;
        const float* p = x + base;

        // rows 2t (a,b) and 2t+1 (c,d): 4 independent 16B loads
        const f32x4 a = *reinterpret_cast<const f32x4*>(p);
        const f32x4 b = *reinterpret_cast<const f32x4*>(p + 4);
        const f32x4 c = *reinterpret_cast<const f32x4*>(p + 56);
        const f32x4 d = *reinterpret_cast<const f32x4*>(p + 60);
        const float rv = r[wid];               // 4 lanes same addr -> broadcast

        // fp64 per-lane sum of 16 elems (tree), then 2-round butterfly in team
        double s = ((((double)a.x + (double)a.y) + ((double)a.z + (double)a.w))
                 +  (((double)b.x + (double)b.y) + ((double)b.z + (double)b.w)))
                 + ((((double)c.x + (double)c.y) + ((double)c.z + (double)c.w))
                 +  (((double)d.x + (double)d.y) + ((double)d.z + (double)d.w)));
        s += __shfl_xor(s, 1, 64);
        s += __shfl_xor(s, 2, 64);

        const float coef = rv / (float)(s + 32.0 * 1e-5);

        __builtin_nontemporal_store(a * coef, reinterpret_cast<f32x4*>(out + base));
        __builtin_nontemporal_store(b * coef, reinterpret_cast<f32x4*>(out + base + 4));
        __builtin_nontemporal_store(c * coef, reinterpret_cast<f32x4*>(out + base + 56));
        __builtin_nontemporal_store(d * coef, reinterpret_cast<f32x4*>(out + base + 60));
    }
}

extern "C" void kernel_launch(void* const* d_in, const int* in_sizes, int n_in,
                              void* d_out, int out_size, void* d_ws, size_t ws_size,
                              hipStream_t stream) {
    const float* x   = (const float*)d_in[0];
    const float* r   = (const float*)d_in[1];
    float*       out = (float*)d_out;
    lrp_pool_kernel<<<BLOCKS, 256, 0, stream>>>(x, r, out);
}

// Round 5
// 38.459 us; speedup vs baseline: 2.4691x; 2.4691x over previous
//
#include <hip/hip_runtime.h>

// LRP m-rule backward through AdaptiveAvgPool2d (56x56 -> 7x7, window 8x8, k=64).
//
// theta = 180deg => COS_T = -1.0 exactly, SIN_T ~ 1.2e-16. The chain collapses:
//   out_i = x_i * r / (Sx + 32*eps),  Sx = window sum (fp64: denominator can
// nearly cancel, min |denom| ~8e-7 over 401K windows). Divide in fp32.
//
// Round-5: one wave = 8 windows, 8-lane team per window; lane owns one full
// window row = 2 contiguous float4 loads (32 B). Butterfly = 3 shuffle rounds
// (xor 1,2,4) within the team. REGULAR stores (round-4's nontemporal stores
// doubled WRITE_SIZE 103->215 MB: NT bypasses L2 write-combining, partial-line
// 32B stores amplify ~2x at HBM. NT on gfx950 only for full-line streams).
//
// Grid: 50176 wave-groups = 7168 waves x 7 iters exact; 1792 blocks x 4 waves
// = 7 blocks/CU exact -> single resident pass, zero CU imbalance.

typedef float f32x4 __attribute__((ext_vector_type(4)));

static constexpr int HW     = 56 * 56;          // 3136
static constexpr int NWIN   = 8192 * 49;        // 401408 windows
static constexpr int NGRP   = NWIN / 8;         // 50176 wave-iterations
static constexpr int BLOCKS = 1792;             // 7 blocks/CU exact
static constexpr int WAVES  = BLOCKS * 4;       // 7168
static constexpr int NITER  = NGRP / WAVES;     // 7 (exact)

__global__ __launch_bounds__(256) void lrp_pool_kernel(
    const float* __restrict__ x,
    const float* __restrict__ r,
    float* __restrict__ out)
{
    const int tid  = threadIdx.x;
    const int lane = tid & 63;
    const int w    = lane >> 3;   // window within the wave's group of 8
    const int t    = lane & 7;    // team lane = window row

    const int g0 = blockIdx.x * 4 + (tid >> 6);

    #pragma unroll
    for (int it = 0; it < NITER; ++it) {
        const int g   = g0 + it * WAVES;
        const int wid = g * 8 + w;
        const int bc  = wid / 49;              // magic-mul div
        const int rem = wid - bc * 49;
        const int ohi = rem / 7;
        const int owi = rem - ohi * 7;

        const int base = bc * HW + (ohi * 8 + t) * 56 + owi * 8;
        const float* p = x + base;

        // one full window row: 2 contiguous 16B loads
        const f32x4 a = *reinterpret_cast<const f32x4*>(p);
        const f32x4 b = *reinterpret_cast<const f32x4*>(p + 4);
        const float rv = r[wid];               // 8 lanes same addr -> broadcast

        // fp64 per-lane row sum (tree), then 3-round butterfly within team
        double s = (((double)a.x + (double)a.y) + ((double)a.z + (double)a.w))
                 + (((double)b.x + (double)b.y) + ((double)b.z + (double)b.w));
        s += __shfl_xor(s, 1, 64);
        s += __shfl_xor(s, 2, 64);
        s += __shfl_xor(s, 4, 64);

        const float coef = rv / (float)(s + 32.0 * 1e-5);

        *reinterpret_cast<f32x4*>(out + base)     = a * coef;
        *reinterpret_cast<f32x4*>(out + base + 4) = b * coef;
    }
}

extern "C" void kernel_launch(void* const* d_in, const int* in_sizes, int n_in,
                              void* d_out, int out_size, void* d_ws, size_t ws_size,
                              hipStream_t stream) {
    const float* x   = (const float*)d_in[0];
    const float* r   = (const float*)d_in[1];
    float*       out = (float*)d_out;
    lrp_pool_kernel<<<BLOCKS, 256, 0, stream>>>(x, r, out);
}